// Round 13
// baseline (535.771 us; speedup 1.0000x reference)
//
#include <hip/hip_runtime.h>

#define H 51
#define TIN 512
#define TTOT 544      // TIN + future(32)
#define BTILE 8
#define AST 88        // ring row stride in shorts (176 B, 16B-aligned)
#define H2ST 13       // sH2f row stride in floats (13 coprime 32)
#define INST 516      // sIn row stride in floats (516%32=4: staging reads conflict-free)
#define SOST 548      // sOut row stride in floats
#define NTHR 1024     // 16 waves: 4 L1a + 4 L1b(+head) + 4 L2a + 4 L2b

typedef __attribute__((ext_vector_type(8))) short short8;
typedef __attribute__((ext_vector_type(4))) float float4v;

#define MFMA __builtin_amdgcn_mfma_f32_16x16x32_bf16

__device__ __forceinline__ float fast_rcp(float x) { return __builtin_amdgcn_rcpf(x); }
__device__ __forceinline__ float sigf(float x)  { return fast_rcp(1.0f + __expf(-x)); }
__device__ __forceinline__ float tanhf_(float x){ return 1.0f - 2.0f * fast_rcp(1.0f + __expf(2.0f * x)); }

__device__ __forceinline__ unsigned short bf16rnd(float x) {
    unsigned int u = __float_as_uint(x);
    return (unsigned short)((u + 0x7fffu + ((u >> 16) & 1u)) >> 16);
}
__device__ __forceinline__ void bf16split(float x, unsigned short& hi, float& lo) {
    unsigned int u  = __float_as_uint(x);
    unsigned int hr = (u + 0x7fffu + ((u >> 16) & 1u)) & 0xffff0000u;
    hi = (unsigned short)(hr >> 16);
    lo = x - __uint_as_float(hr);          // exact residual
}

// L1 k-space (A = sA1): 0..50 h1 | 51 x | 52..63 zero.
__device__ __forceinline__ float b1val(int k, int u, int g,
                                       const float* Whh1, const float* Wih1) {
    if (u >= H) return 0.0f;
    const int r = g * H + u;
    if (k < H)  return Whh1[r * H + k];
    if (k == H) return Wih1[r];
    return 0.0f;
}
// L2 k-space: 0..50 h1 (sA1) | 51..63 zero | 64..114 h2 (sA2 cols 0..50).
__device__ __forceinline__ float b2val(int k, int u, int g,
                                       const float* Wih2, const float* Whh2) {
    if (u >= H) return 0.0f;
    const int r = g * H + u;
    if (k < H) return Wih2[r * H + k];
    if (k >= 64 && k < 64 + H) return Whh2[r * H + (k - 64)];
    return 0.0f;
}

// R26 (resubmit; previous round was an infra failure, no data) = R21 barrier
// structure (flag-sync arc CLOSED: R22/R25 both slower -- the ~700cyc/step
// stall is latency-hiding starvation, not rendezvous cost) + j-SPLIT for TLP:
//  - 16 waves, 4/SIMD (was 3, one mostly idle). Per-wave trans chain 20->10.
//  - Duplicated per half: the 8/16 MFMAs + A-ring ds_reads (MFMA pipe at 27%
//    has room). NOT duplicated (unlike failed R16 block-split): staging, head,
//    LDS footprint, barrier count.
//  - aux waves gone; head/staging/feedback folded into L1b (waves 4-7).
//  - sIn stride 516: teacher staging read (8 lanes, stride-512 rows) was
//    32-bank-aliased -> now conflict-free.
// Numerics VERBATIM R21 per row; bf16rnd == v_cvt_pk RNE (pinned R15-R17).
// absmax must stay exactly 2.441406e-4. Revert if >=340us: R21 (346.7us);
// null result => stall not TLP-hideable => structural floor.
__global__ __launch_bounds__(NTHR)
__attribute__((amdgpu_waves_per_eu(4, 4)))
void lstm_seq(
    const float* __restrict__ input,   // [2048][512]
    const float* __restrict__ W_ih1,   // [204]
    const float* __restrict__ W_hh1,   // [204][51]
    const float* __restrict__ b_ih1,   // [204]
    const float* __restrict__ b_hh1,   // [204]
    const float* __restrict__ W_ih2,   // [204][51]
    const float* __restrict__ W_hh2,   // [204][51]
    const float* __restrict__ b_ih2,   // [204]
    const float* __restrict__ b_hh2,   // [204]
    const float* __restrict__ W_lin,   // [51]
    const float* __restrict__ b_lin,   // [1]
    float* __restrict__ out)           // [2048][544]
{
    __shared__ __align__(16) unsigned short sA1h[2][16][AST];  // h1 ring + x col 51
    __shared__ __align__(16) unsigned short sA2h[2][16][AST];  // h2 ring
    __shared__ float sH2f[2][64][H2ST];                        // h2 f32 for head
    __shared__ __align__(8) float sXlo[2][8];                  // x bf16-residual
    __shared__ float sWlin[64];
    __shared__ __align__(16) float sIn[BTILE][INST];           // staged input tile
    __shared__ __align__(16) float sOut[BTILE][SOST];          // buffered outputs

    const int tid  = threadIdx.x;
    const int lane = tid & 63;
    const int wv   = tid >> 6;             // 0..15
    const int grp  = wv >> 2;              // 0=L1a 1=L1b(+head) 2=L2a 3=L2b
    const int ut   = wv & 3;
    const int jj   = grp & 1;              // which batch-row of the quad pair
    const int quad = lane >> 4;
    const int kq   = quad * 8;
    const int nl   = lane & 15;
    const int u    = ut * 16 + nl;
    const int ur   = (u < H) ? u : (H - 1);
    const int b0   = blockIdx.x * BTILE;
    const float blin = b_lin[0];
    const int rowAj = (quad & 1) * 4 + (quad >> 1) * 2 + jj;  // my batch-row
    const int arowj = quad * 4 + jj;       // my A-ring row (relocated map)
    const int kc   = lane & 31;            // head: k-phase
    const int bhead= 2 * ut + (lane >> 5); // head: this lane's batch

    // ---- LDS init + input staging ----
    {
        unsigned short* p0 = &sA1h[0][0][0];
        unsigned short* p2 = &sA2h[0][0][0];
        for (int i = tid; i < 2 * 16 * AST; i += NTHR) { p0[i] = 0; p2[i] = 0; }
        float* pf = &sH2f[0][0][0];
        for (int i = tid; i < 2 * 64 * H2ST; i += NTHR) pf[i] = 0.0f;
        if (tid < 16) sXlo[tid >> 3][tid & 7] = 0.0f;
        if (tid < 64) sWlin[tid] = (tid < H) ? W_lin[tid] : 0.0f;
        // stage input tile: 8 rows x 512 f32 = 1024 float4, 1/thread, coalesced
        {
            const int r = tid >> 7, c = tid & 127;
            *(float4v*)&sIn[r][c * 4] =
                *(const float4v*)&input[(size_t)(b0 + r) * TIN + c * 4];
        }
    }
    __syncthreads();
    if (tid < 8) {   // x(0) -> slot 0: bf16 hi in A col 51 (relocated row), residual
        unsigned short hh; float lo;
        bf16split(sIn[tid][0], hh, lo);
        sA1h[0][(tid & 2) ? tid + 6 : tid][51] = hh;
        sXlo[0][tid] = lo;
    }
    __syncthreads();

    if (grp < 2) {
        // ================= LAYER-1 WAVES (a: j=0, b: j=1 + head/staging) ======
        short8 B1h[4][2];
        float zb1[4], wxf[4];
        #pragma unroll
        for (int g = 0; g < 4; ++g) {
            #pragma unroll
            for (int kt = 0; kt < 2; ++kt)
                #pragma unroll
                for (int j = 0; j < 8; ++j)
                    B1h[g][kt][j] = (short)bf16rnd(b1val(kt * 32 + kq + j, u, g, W_hh1, W_ih1));
            const int r = g * H + ur;
            zb1[g] = b_ih1[r] + b_hh1[r];
            wxf[g] = W_ih1[r];             // f32 x-weight for residual fix
        }
        float c1 = 0.0f;

        auto l1work = [&](int rs, int ws) __attribute__((always_inline)) {
            short8 a0h = *(const short8*)&sA1h[rs][nl][kq];
            short8 a1h = *(const short8*)&sA1h[rs][nl][32 + kq];
            float xr = sXlo[rs][rowAj];    // residual for my row
            float4v C[4];
            #pragma unroll
            for (int g = 0; g < 4; ++g) {
                float4v c = {zb1[g], zb1[g], zb1[g], zb1[g]};
                c = MFMA(a0h, B1h[g][0], c, 0, 0, 0);
                c = MFMA(a1h, B1h[g][1], c, 0, 0, 0);
                C[g] = c;
            }
            float I = sigf  (C[0][jj] + wxf[0] * xr);
            float F = sigf  (C[1][jj] + wxf[1] * xr);
            float G = tanhf_(C[2][jj] + wxf[2] * xr);
            float O = sigf  (C[3][jj] + wxf[3] * xr);
            c1 = F * c1 + I * G;
            float h1v = O * tanhf_(c1);
            if (u < H) sA1h[ws][arowj][u] = bf16rnd(h1v);
        };
        auto headw = [&](int slot, int outt) __attribute__((always_inline)) -> float {
            float p = sWlin[kc]      * sH2f[slot][kc][bhead]
                    + sWlin[kc + 32] * sH2f[slot][kc + 32][bhead];
            p += __shfl_xor(p, 1);  p += __shfl_xor(p, 2);  p += __shfl_xor(p, 4);
            p += __shfl_xor(p, 8);  p += __shfl_xor(p, 16);
            float val = p + blin;
            if (kc == 0) sOut[bhead][outt] = val;
            return val;
        };

        // ---- teacher phase (1 barrier/step) ----
        if (grp == 0) {
            for (int s = 0; s < TIN; ++s) {
                if ((s & 1) == 0) l1work(0, 1);
                else              l1work(1, 0);
                __syncthreads();
            }
        } else {
            for (int s = 0; s < TIN; ++s) {
                const int rs = s & 1, ws = rs ^ 1;
                float xpre = 0.0f;
                const bool doX = (wv == 4) && (lane < 8) && (s + 1 < TIN);
                if (doX) xpre = sIn[lane][s + 1];
                if (s >= 2) headw(ws, s - 2);      // sH2f[ws] = h2(s-2)
                l1work(rs, ws);
                if (doX) {
                    unsigned short hh; float lo; bf16split(xpre, hh, lo);
                    sA1h[ws][(lane & 2) ? lane + 6 : lane][51] = hh;
                    sXlo[ws][lane] = lo;
                }
                __syncthreads();
            }
        }
        // ---- serial autoregressive tail ----
        for (int s = TIN; s <= TTOT; ++s) {
            const int rs = s & 1, ws = rs ^ 1;
            __syncthreads();               // B1: L2 finished h2(s-1) -> sH2f[rs]
            if (grp == 1) {
                float val = headw(rs, s - 1);
                if (kc == 0 && s < TTOT) { // feedback x(s) = out(s-1)
                    unsigned short hh; float lo; bf16split(val, hh, lo);
                    sA1h[rs][(bhead & 2) ? bhead + 6 : bhead][51] = hh;
                    sXlo[rs][bhead] = lo;
                }
                if (s == TIN) headw(ws, s - 2);   // gap: out(TIN-2)
            }
            __syncthreads();               // B2: x(s) visible
            if (s < TTOT) l1work(rs, ws);
            __syncthreads();               // B3: h1(s) visible
        }
    } else {
        // ================= LAYER-2 WAVES (a: j=0, b: j=1) =====================
        short8 B2h[4][4];
        float zb2[4];
        #pragma unroll
        for (int g = 0; g < 4; ++g) {
            #pragma unroll
            for (int kt = 0; kt < 4; ++kt)
                #pragma unroll
                for (int j = 0; j < 8; ++j)
                    B2h[g][kt][j] = (short)bf16rnd(b2val(kt * 32 + kq + j, u, g, W_ih2, W_hh2));
            const int r = g * H + ur;
            zb2[g] = b_ih2[r] + b_hh2[r];
        }
        float c2 = 0.0f;

        auto l2work = [&](int rs, int ws) __attribute__((always_inline)) {
            short8 f0h = *(const short8*)&sA1h[rs][nl][kq];
            short8 f1h = *(const short8*)&sA1h[rs][nl][32 + kq];
            short8 f2h = *(const short8*)&sA2h[rs][nl][kq];
            short8 f3h = *(const short8*)&sA2h[rs][nl][32 + kq];
            float4v C[4];
            #pragma unroll
            for (int g = 0; g < 4; ++g) {
                float4v c = {zb2[g], zb2[g], zb2[g], zb2[g]};
                c = MFMA(f0h, B2h[g][0], c, 0, 0, 0);
                c = MFMA(f1h, B2h[g][1], c, 0, 0, 0);
                c = MFMA(f2h, B2h[g][2], c, 0, 0, 0);
                c = MFMA(f3h, B2h[g][3], c, 0, 0, 0);
                C[g] = c;
            }
            float I = sigf  (C[0][jj]);
            float F = sigf  (C[1][jj]);
            float G = tanhf_(C[2][jj]);
            float O = sigf  (C[3][jj]);
            c2 = F * c2 + I * G;
            float h2v = O * tanhf_(c2);
            if (u < H) {
                sA2h[ws][arowj][u] = bf16rnd(h2v);
                sH2f[rs][u][rowAj] = h2v;
            }
        };

        // ---- teacher phase ----
        for (int s = 0; s < TIN; ++s) {
            if ((s & 1) == 0) { if (s) l2work(0, 1); }
            else              l2work(1, 0);
            __syncthreads();
        }
        // ---- serial tail ----
        for (int s = TIN; s <= TTOT; ++s) {
            const int rs = s & 1, ws = rs ^ 1;
            l2work(rs, ws);
            __syncthreads();               // B1
            __syncthreads();               // B2
            __syncthreads();               // B3
        }
    }

    // ---- write buffered outputs back: 8 rows x 544 f32, float4 coalesced ----
    __syncthreads();
    for (int i = tid; i < BTILE * (TTOT / 4); i += NTHR) {
        const int r = i / (TTOT / 4);
        const int c = i - r * (TTOT / 4);
        *(float4v*)&out[(size_t)(b0 + r) * TTOT + c * 4] =
            *(const float4v*)&sOut[r][c * 4];
    }
}

extern "C" void kernel_launch(void* const* d_in, const int* in_sizes, int n_in,
                              void* d_out, int out_size, void* d_ws, size_t ws_size,
                              hipStream_t stream) {
    const float* input = (const float*)d_in[0];
    const float* W_ih1 = (const float*)d_in[1];
    const float* W_hh1 = (const float*)d_in[2];
    const float* b_ih1 = (const float*)d_in[3];
    const float* b_hh1 = (const float*)d_in[4];
    const float* W_ih2 = (const float*)d_in[5];
    const float* W_hh2 = (const float*)d_in[6];
    const float* b_ih2 = (const float*)d_in[7];
    const float* b_hh2 = (const float*)d_in[8];
    const float* W_lin = (const float*)d_in[9];
    const float* b_lin = (const float*)d_in[10];
    // d_in[11] = future (=32), compiled in.
    float* out = (float*)d_out;

    lstm_seq<<<dim3(256), dim3(NTHR), 0, stream>>>(input, W_ih1, W_hh1, b_ih1, b_hh1,
                                                   W_ih2, W_hh2, b_ih2, b_hh2,
                                                   W_lin, b_lin, out);
}

// Round 14
// 407.432 us; speedup vs baseline: 1.3150x; 1.3150x over previous
//
#include <hip/hip_runtime.h>

#define H 51
#define TIN 512
#define TTOT 544      // TIN + future(32)
#define BTILE 8
#define AST 88        // ring row stride in shorts (176 B, 16B-aligned)
#define H2ST 9        // sH2f row stride in floats (9 coprime 32 -> headw conflict-free)
#define INST 516      // sIn row stride in floats
#define SOST 548      // sOut row stride in floats
#define NTHR 768      // 12 waves: 4 L1 + 4 L2 + 4 aux

typedef __attribute__((ext_vector_type(8))) short short8;
typedef __attribute__((ext_vector_type(4))) float float4v;

#define MFMA __builtin_amdgcn_mfma_f32_16x16x32_bf16

__device__ __forceinline__ float fast_rcp(float x) { return __builtin_amdgcn_rcpf(x); }
__device__ __forceinline__ float sigf(float x)  { return fast_rcp(1.0f + __expf(-x)); }
__device__ __forceinline__ float tanhf_(float x){ return 1.0f - 2.0f * fast_rcp(1.0f + __expf(2.0f * x)); }

__device__ __forceinline__ unsigned short bf16rnd(float x) {
    unsigned int u = __float_as_uint(x);
    return (unsigned short)((u + 0x7fffu + ((u >> 16) & 1u)) >> 16);
}
__device__ __forceinline__ unsigned int bf16pk(float a, float b) {
    unsigned int r;
    asm("v_cvt_pk_bf16_f32 %0, %1, %2" : "=v"(r) : "v"(a), "v"(b));
    return r;
}
__device__ __forceinline__ void bf16split(float x, unsigned short& hi, float& lo) {
    unsigned int u  = __float_as_uint(x);
    unsigned int hr = (u + 0x7fffu + ((u >> 16) & 1u)) & 0xffff0000u;
    hi = (unsigned short)(hr >> 16);
    lo = x - __uint_as_float(hr);          // exact residual
}

// L1 k-space (A = sA1): 0..50 h1 | 51 x | 52..63 zero.
__device__ __forceinline__ float b1val(int k, int u, int g,
                                       const float* Whh1, const float* Wih1) {
    if (u >= H) return 0.0f;
    const int r = g * H + u;
    if (k < H)  return Whh1[r * H + k];
    if (k == H) return Wih1[r];
    return 0.0f;
}
// L2 k-space: 0..50 h1 (sA1) | 51..63 zero | 64..114 h2 (sA2 cols 0..50).
__device__ __forceinline__ float b2val(int k, int u, int g,
                                       const float* Wih2, const float* Whh2) {
    if (u >= H) return 0.0f;
    const int r = g * H + u;
    if (k < H) return Wih2[r * H + k];
    if (k >= 64 && k < 64 + H) return Whh2[r * H + (k - 64)];
    return 0.0f;
}

// R27 = R21 arithmetic VERBATIM + windowed sync. Post-R26 model: interval =
// chain(~500) + sync overhead(~1000); R22~=R25~=440 despite opposite protocols
// => ALL-LANE polling was the flag cost, and the 12-wave per-step barrier is
// the barrier cost. Only INTRA-group sync is needed per step (h1/h2 all-to-all
// within L1/L2's 4 waves); cross-group deps pipeline.
//  - Teacher: barrier every 2 steps (256 windows). Window w: L1 does steps
//    {2w,2w+1}; L2 does {2w-2,2w-1} (one window behind); aux heads {2w-4,2w-3}
//    + stages x(2w+2),x(2w+3). Cross-group deps all land pre-barrier (audited).
//  - Intra-group per-step sync: group counter in LDS, polled by LANE 0 ONLY
//    (+s_sleep) -- 1/64th of R22/R25's poll traffic -- bumped after lgkmcnt(0).
//    Semantics = R25's proven self-spin (cnt >= 4*s before step s).
//  - Slots: h1(s)/x(s+1)/sH2f(s) @ s&3 rings; h2(s) @ s&1. All concurrent
//    reader/writer pairs slot- or column-disjoint; col-51-x-while-L2-reads is
//    the R22-proven-safe zero-weight race.
//  - Drain: D1 {L2 510,511 | heads 508,509}, D2 {heads 510,511 + feedback
//    x(512)}, then R21-style 3-barrier coupled tail s=512..543.
// absmax must stay exactly 2.441406e-4. Revert if hang or >=340us: R21 (346.7).
__global__ __launch_bounds__(NTHR)
__attribute__((amdgpu_waves_per_eu(3, 3)))
void lstm_seq(
    const float* __restrict__ input,   // [2048][512]
    const float* __restrict__ W_ih1,   // [204]
    const float* __restrict__ W_hh1,   // [204][51]
    const float* __restrict__ b_ih1,   // [204]
    const float* __restrict__ b_hh1,   // [204]
    const float* __restrict__ W_ih2,   // [204][51]
    const float* __restrict__ W_hh2,   // [204][51]
    const float* __restrict__ b_ih2,   // [204]
    const float* __restrict__ b_hh2,   // [204]
    const float* __restrict__ W_lin,   // [51]
    const float* __restrict__ b_lin,   // [1]
    float* __restrict__ out)           // [2048][544]
{
    __shared__ __align__(16) unsigned short sA1h[4][16][AST];  // h1(s)@s&3 + x(s+1) col51
    __shared__ __align__(16) unsigned short sA2h[2][16][AST];  // h2(s)@s&1
    __shared__ float sH2f[4][64][H2ST];                        // h2(s) f32 @s&3
    __shared__ __align__(8) float sXlo[4][8];                  // x residual, slot=(s-1)&3
    __shared__ float sWlin[64];
    __shared__ __align__(16) float sIn[BTILE][INST];           // staged input tile
    __shared__ __align__(16) float sOut[BTILE][SOST];          // buffered outputs
    __shared__ int sCnt[2];                                    // 0=L1 1=L2 group counters

    const int tid  = threadIdx.x;
    const int lane = tid & 63;
    const int wv   = tid >> 6;             // 0..11
    const int grp  = wv >> 2;              // 0=L1 1=L2 2=aux
    const int ut   = wv & 3;
    const int quad = lane >> 4;
    const int kq   = quad * 8;
    const int nl   = lane & 15;
    const int u    = ut * 16 + nl;
    const int ur   = (u < H) ? u : (H - 1);
    const int b0   = blockIdx.x * BTILE;
    const float blin = b_lin[0];
    const int rowA = (quad & 1) * 4 + (quad >> 1) * 2;   // this quad's 2 batch-rows
    const int arow = quad * 4;             // A-ring row this quad WRITES (relocated)
    const int kc   = lane & 31;            // head: k-phase
    const int bhead= 2 * ut + (lane >> 5); // head: this lane's batch

    volatile int* vc = (volatile int*)sCnt;
    auto gwait = [&](int idx, int v) __attribute__((always_inline)) {
        if (lane == 0) {
            while (vc[idx] < v) __builtin_amdgcn_s_sleep(1);
        }
        asm volatile("" ::: "memory");     // no LDS access reordered above
    };
    auto gbump = [&](int idx) __attribute__((always_inline)) {
        asm volatile("s_waitcnt lgkmcnt(0)" ::: "memory");  // my writes land first
        if (lane == 0) atomicAdd(&sCnt[idx], 1);
    };

    // ---- LDS init + input staging ----
    {
        unsigned short* p0 = &sA1h[0][0][0];
        for (int i = tid; i < 4 * 16 * AST; i += NTHR) p0[i] = 0;
        unsigned short* p2 = &sA2h[0][0][0];
        for (int i = tid; i < 2 * 16 * AST; i += NTHR) p2[i] = 0;
        float* pf = &sH2f[0][0][0];
        for (int i = tid; i < 4 * 64 * H2ST; i += NTHR) pf[i] = 0.0f;
        if (tid < 32) sXlo[tid >> 3][tid & 7] = 0.0f;
        if (tid < 64) sWlin[tid] = (tid < H) ? W_lin[tid] : 0.0f;
        if (tid < 2) sCnt[tid] = 0;
        for (int i = tid; i < BTILE * (TIN / 4); i += NTHR) {
            const int r = i >> 7, c = i & 127;
            *(float4v*)&sIn[r][c * 4] =
                *(const float4v*)&input[(size_t)(b0 + r) * TIN + c * 4];
        }
    }
    __syncthreads();
    if (tid < 16) {  // bootstrap x(0)->slot 3, x(1)->slot 0 (slot=(s-1)&3), col 51
        const int st = tid >> 3, b = tid & 7;
        unsigned short hh; float lo;
        bf16split(sIn[b][st], hh, lo);
        sA1h[(st - 1) & 3][(b & 2) ? b + 6 : b][51] = hh;
        sXlo[(st - 1) & 3][b] = lo;
    }
    __syncthreads();

    if (grp == 0) {
        // ================= LAYER-1 WAVES =================
        short8 B1h[4][2];
        float zb1[4], wxf[4];
        #pragma unroll
        for (int g = 0; g < 4; ++g) {
            #pragma unroll
            for (int kt = 0; kt < 2; ++kt)
                #pragma unroll
                for (int j = 0; j < 8; ++j)
                    B1h[g][kt][j] = (short)bf16rnd(b1val(kt * 32 + kq + j, u, g, W_hh1, W_ih1));
            const int r = g * H + ur;
            zb1[g] = b_ih1[r] + b_hh1[r];
            wxf[g] = W_ih1[r];             // f32 x-weight for residual fix
        }
        float c1[2] = {0, 0};

        auto l1work = [&](int rs, int ws) __attribute__((always_inline)) {
            short8 a0h = *(const short8*)&sA1h[rs][nl][kq];
            short8 a1h = *(const short8*)&sA1h[rs][nl][32 + kq];
            float2 xl = *(const float2*)&sXlo[rs][rowA];
            float4v C[4];
            #pragma unroll
            for (int g = 0; g < 4; ++g) {
                float4v c = {zb1[g], zb1[g], zb1[g], zb1[g]};
                c = MFMA(a0h, B1h[g][0], c, 0, 0, 0);
                c = MFMA(a1h, B1h[g][1], c, 0, 0, 0);
                C[g] = c;
            }
            float h1v[2];
            #pragma unroll
            for (int j = 0; j < 2; ++j) {
                const float xr = j ? xl.y : xl.x;
                float I = sigf  (C[0][j] + wxf[0] * xr);
                float F = sigf  (C[1][j] + wxf[1] * xr);
                float G = tanhf_(C[2][j] + wxf[2] * xr);
                float O = sigf  (C[3][j] + wxf[3] * xr);
                c1[j] = F * c1[j] + I * G;
                h1v[j] = O * tanhf_(c1[j]);
            }
            if (u < H) {
                const unsigned int pk = bf16pk(h1v[0], h1v[1]);
                sA1h[ws][arow][u]     = (unsigned short)pk;
                sA1h[ws][arow + 1][u] = (unsigned short)(pk >> 16);
            }
        };

        // ---- teacher: 256 windows of 2 steps ----
        for (int w = 0; w < TIN / 2; ++w) {
            const int s0 = 2 * w;
            gwait(0, 4 * s0);
            l1work((s0 - 1) & 3, s0 & 3);
            gbump(0);
            gwait(0, 4 * (s0 + 1));        // intra-window: all L1 waves thru s0
            l1work(s0 & 3, (s0 + 1) & 3);
            gbump(0);
            __syncthreads();
        }
        // ---- drain windows D1, D2 (idle for L1) ----
        __syncthreads();                   // D1
        __syncthreads();                   // D2
        // ---- coupled tail ----
        for (int s = TIN; s < TTOT; ++s) {
            l1work((s - 1) & 3, s & 3);
            __syncthreads();               // h1(s) visible
            __syncthreads();               // L2 phase
            __syncthreads();               // aux phase
        }
    } else if (grp == 1) {
        // ================= LAYER-2 WAVES =================
        short8 B2h[4][4];
        float zb2[4];
        #pragma unroll
        for (int g = 0; g < 4; ++g) {
            #pragma unroll
            for (int kt = 0; kt < 4; ++kt)
                #pragma unroll
                for (int j = 0; j < 8; ++j)
                    B2h[g][kt][j] = (short)bf16rnd(b2val(kt * 32 + kq + j, u, g, W_ih2, W_hh2));
            const int r = g * H + ur;
            zb2[g] = b_ih2[r] + b_hh2[r];
        }
        float c2[2] = {0, 0};

        // h2(s): read h1(s)@sA1h[s&3], h2(s-1)@sA2h[(s-1)&1];
        // write sA2h[s&1], sH2f[s&3].
        auto l2work = [&](int ra, int rh, int wh, int wf) __attribute__((always_inline)) {
            short8 f0h = *(const short8*)&sA1h[ra][nl][kq];
            short8 f1h = *(const short8*)&sA1h[ra][nl][32 + kq];
            short8 f2h = *(const short8*)&sA2h[rh][nl][kq];
            short8 f3h = *(const short8*)&sA2h[rh][nl][32 + kq];
            float4v C[4];
            #pragma unroll
            for (int g = 0; g < 4; ++g) {
                float4v c = {zb2[g], zb2[g], zb2[g], zb2[g]};
                c = MFMA(f0h, B2h[g][0], c, 0, 0, 0);
                c = MFMA(f1h, B2h[g][1], c, 0, 0, 0);
                c = MFMA(f2h, B2h[g][2], c, 0, 0, 0);
                c = MFMA(f3h, B2h[g][3], c, 0, 0, 0);
                C[g] = c;
            }
            float h2v[2];
            #pragma unroll
            for (int j = 0; j < 2; ++j) {
                float I = sigf  (C[0][j]);
                float F = sigf  (C[1][j]);
                float G = tanhf_(C[2][j]);
                float O = sigf  (C[3][j]);
                c2[j] = F * c2[j] + I * G;
                h2v[j] = O * tanhf_(c2[j]);
            }
            if (u < H) {
                const unsigned int pk = bf16pk(h2v[0], h2v[1]);
                sA2h[wh][arow][u]     = (unsigned short)pk;
                sA2h[wh][arow + 1][u] = (unsigned short)(pk >> 16);
                sH2f[wf][u][rowA]     = h2v[0];
                sH2f[wf][u][rowA + 1] = h2v[1];
            }
        };
        auto l2step = [&](int s) __attribute__((always_inline)) {
            gwait(1, 4 * s);
            l2work(s & 3, (s - 1) & 1, s & 1, s & 3);
            gbump(1);
        };

        // ---- teacher: window w does steps {2w-2, 2w-1} (w>=1) ----
        for (int w = 0; w < TIN / 2; ++w) {
            if (w >= 1) { l2step(2 * w - 2); l2step(2 * w - 1); }
            __syncthreads();
        }
        // ---- D1: catch up h2(510), h2(511) ----
        l2step(TIN - 2);
        l2step(TIN - 1);
        __syncthreads();                   // D1
        __syncthreads();                   // D2
        // ---- coupled tail ----
        for (int s = TIN; s < TTOT; ++s) {
            __syncthreads();               // h1(s) ready
            l2work(s & 3, (s - 1) & 1, s & 1, s & 3);
            __syncthreads();               // h2(s) visible
            __syncthreads();               // aux phase
        }
    } else {
        // ================= AUX WAVES: head + x staging + feedback =================
        auto headw = [&](int slot, int outt) __attribute__((always_inline)) -> float {
            float p = sWlin[kc]      * sH2f[slot][kc][bhead]
                    + sWlin[kc + 32] * sH2f[slot][kc + 32][bhead];
            p += __shfl_xor(p, 1);  p += __shfl_xor(p, 2);  p += __shfl_xor(p, 4);
            p += __shfl_xor(p, 8);  p += __shfl_xor(p, 16);
            float val = p + blin;
            if (kc == 0) sOut[bhead][outt] = val;
            return val;
        };

        // ---- teacher: window w: heads {2w-4, 2w-3}; stage x(2w+2), x(2w+3) ----
        for (int w = 0; w < TIN / 2; ++w) {
            if (w >= 2) {
                headw((2 * w - 4) & 3, 2 * w - 4);
                headw((2 * w - 3) & 3, 2 * w - 3);
            }
            if (wv == 8 && lane < 16) {
                const int ts = 2 * w + 2 + (lane >> 3);
                const int b  = lane & 7;
                if (ts < TIN) {
                    unsigned short hh; float lo;
                    bf16split(sIn[b][ts], hh, lo);
                    sA1h[(ts - 1) & 3][(b & 2) ? b + 6 : b][51] = hh;
                    sXlo[(ts - 1) & 3][b] = lo;
                }
            }
            __syncthreads();
        }
        // ---- D1: heads 508, 509 ----
        headw((TIN - 4) & 3, TIN - 4);
        headw((TIN - 3) & 3, TIN - 3);
        __syncthreads();                   // D1 (L2 wrote h2(510),h2(511))
        // ---- D2: heads 510, 511 + feedback x(512) ----
        headw((TIN - 2) & 3, TIN - 2);
        {
            float val = headw((TIN - 1) & 3, TIN - 1);
            if (kc == 0) {                 // x(512) -> slot (512-1)&3 = 3
                unsigned short hh; float lo; bf16split(val, hh, lo);
                sA1h[(TIN - 1) & 3][(bhead & 2) ? bhead + 6 : bhead][51] = hh;
                sXlo[(TIN - 1) & 3][bhead] = lo;
            }
        }
        __syncthreads();                   // D2
        // ---- coupled tail ----
        for (int s = TIN; s < TTOT; ++s) {
            __syncthreads();               // h1(s)
            __syncthreads();               // h2(s)
            float val = headw(s & 3, s);
            if (kc == 0 && s + 1 < TTOT) { // feedback x(s+1) -> slot s&3
                unsigned short hh; float lo; bf16split(val, hh, lo);
                sA1h[s & 3][(bhead & 2) ? bhead + 6 : bhead][51] = hh;
                sXlo[s & 3][bhead] = lo;
            }
            __syncthreads();
        }
    }

    // ---- all groups converge, then write buffered outputs back ----
    __syncthreads();
    for (int i = tid; i < BTILE * (TTOT / 4); i += NTHR) {
        const int r = i / (TTOT / 4);
        const int c = i - r * (TTOT / 4);
        *(float4v*)&out[(size_t)(b0 + r) * TTOT + c * 4] =
            *(const float4v*)&sOut[r][c * 4];
    }
}

extern "C" void kernel_launch(void* const* d_in, const int* in_sizes, int n_in,
                              void* d_out, int out_size, void* d_ws, size_t ws_size,
                              hipStream_t stream) {
    const float* input = (const float*)d_in[0];
    const float* W_ih1 = (const float*)d_in[1];
    const float* W_hh1 = (const float*)d_in[2];
    const float* b_ih1 = (const float*)d_in[3];
    const float* b_hh1 = (const float*)d_in[4];
    const float* W_ih2 = (const float*)d_in[5];
    const float* W_hh2 = (const float*)d_in[6];
    const float* b_ih2 = (const float*)d_in[7];
    const float* b_hh2 = (const float*)d_in[8];
    const float* W_lin = (const float*)d_in[9];
    const float* b_lin = (const float*)d_in[10];
    // d_in[11] = future (=32), compiled in.
    float* out = (float*)d_out;

    lstm_seq<<<dim3(256), dim3(NTHR), 0, stream>>>(input, W_ih1, W_hh1, b_ih1, b_hh1,
                                                   W_ih2, W_hh2, b_ih2, b_hh2,
                                                   W_lin, b_lin, out);
}

// Round 15
// 386.208 us; speedup vs baseline: 1.3873x; 1.0550x over previous
//
#include <hip/hip_runtime.h>

#define H 51
#define TIN 512
#define TTOT 544      // TIN + future(32)
#define BTILE 8
#define AST 88        // ring row stride in shorts (176 B, 16B-aligned)
#define H2ST 13       // sH2f row stride in floats (13 coprime 32)
#define INST 516      // sIn row stride in floats (516%32=4: staging reads conflict-free)
#define SOST 548      // sOut row stride in floats
#define NTHR 768      // 12 waves: 4 L1 + 4 L2 + 4 aux

typedef __attribute__((ext_vector_type(8))) short short8;
typedef __attribute__((ext_vector_type(4))) float float4v;

#define MFMA __builtin_amdgcn_mfma_f32_16x16x32_bf16

__device__ __forceinline__ float fast_rcp(float x) { return __builtin_amdgcn_rcpf(x); }
__device__ __forceinline__ float sigf(float x)  { return fast_rcp(1.0f + __expf(-x)); }
__device__ __forceinline__ float tanhf_(float x){ return 1.0f - 2.0f * fast_rcp(1.0f + __expf(2.0f * x)); }

__device__ __forceinline__ unsigned short bf16rnd(float x) {
    unsigned int u = __float_as_uint(x);
    return (unsigned short)((u + 0x7fffu + ((u >> 16) & 1u)) >> 16);
}
// RNE pack of two f32 -> two bf16 in one instruction (same rounding as bf16rnd)
__device__ __forceinline__ unsigned int bf16pk(float a, float b) {
    unsigned int r;
    asm("v_cvt_pk_bf16_f32 %0, %1, %2" : "=v"(r) : "v"(a), "v"(b));
    return r;
}
__device__ __forceinline__ void bf16split(float x, unsigned short& hi, float& lo) {
    unsigned int u  = __float_as_uint(x);
    unsigned int hr = (u + 0x7fffu + ((u >> 16) & 1u)) & 0xffff0000u;
    hi = (unsigned short)(hr >> 16);
    lo = x - __uint_as_float(hr);          // exact residual
}

// L1 k-space (A = sA1): 0..50 h1 | 51 x | 52..63 zero.
__device__ __forceinline__ float b1val(int k, int u, int g,
                                       const float* Whh1, const float* Wih1) {
    if (u >= H) return 0.0f;
    const int r = g * H + u;
    if (k < H)  return Whh1[r * H + k];
    if (k == H) return Wih1[r];
    return 0.0f;
}
// L2 k-space: 0..50 h1 (sA1) | 51..63 zero | 64..114 h2 (sA2 cols 0..50).
__device__ __forceinline__ float b2val(int k, int u, int g,
                                       const float* Wih2, const float* Whh2) {
    if (u >= H) return 0.0f;
    const int r = g * H + u;
    if (k < H) return Wih2[r * H + k];
    if (k >= 64 && k < 64 + H) return Whh2[r * H + (k - 64)];
    return 0.0f;
}

// R28 = TERMINAL REVERT to R21 (best verified: 346.7us counter, absmax
// 2.441406e-4 exact) + the one zero-risk R27 carryover: INST=516 sIn pad.
// Closed arcs (all regressed vs R21): R16 block-split (+137us, M-waste tax);
// R22/R25 all-lane flag-sync (+90/100, poll cost); R26 j-split TLP (+183,
// duplicated MFMA/ds_read + 16-wave barriers); R27 windowed barriers (+21,
// gwait/gbump overhead exceeds barrier savings). Numerics FROZEN (R18-R20:
// any non-bit-exact cell rewrite is amplified to O(0.1) by the 32-step
// autoregressive tail). Structure: 12 waves (4 L1 + 4 L2 + 4 aux), 2-slot
// rings, 1 barrier/step teacher, 3-barrier/step tail, LDS-only steady state.
// This is the structural floor of the design space explored: interval
// ~1530 cyc/step = ~640 trans-pipe (frozen) + ~400 chain + ~400 issue +
// barrier convergence; no pipe saturated, every restructuring regressed.
__global__ __launch_bounds__(NTHR)
__attribute__((amdgpu_waves_per_eu(3, 3)))
void lstm_seq(
    const float* __restrict__ input,   // [2048][512]
    const float* __restrict__ W_ih1,   // [204]
    const float* __restrict__ W_hh1,   // [204][51]
    const float* __restrict__ b_ih1,   // [204]
    const float* __restrict__ b_hh1,   // [204]
    const float* __restrict__ W_ih2,   // [204][51]
    const float* __restrict__ W_hh2,   // [204][51]
    const float* __restrict__ b_ih2,   // [204]
    const float* __restrict__ b_hh2,   // [204]
    const float* __restrict__ W_lin,   // [51]
    const float* __restrict__ b_lin,   // [1]
    float* __restrict__ out)           // [2048][544]
{
    __shared__ __align__(16) unsigned short sA1h[2][16][AST];  // h1 ring + x col 51
    __shared__ __align__(16) unsigned short sA2h[2][16][AST];  // h2 ring
    __shared__ float sH2f[2][64][H2ST];                        // h2 f32 for head
    __shared__ __align__(8) float sXlo[2][8];                  // x bf16-residual
    __shared__ float sWlin[64];
    __shared__ __align__(16) float sIn[BTILE][INST];           // staged input tile
    __shared__ __align__(16) float sOut[BTILE][SOST];          // buffered outputs

    const int tid  = threadIdx.x;
    const int lane = tid & 63;
    const int wv   = tid >> 6;             // 0..11
    const int ut   = wv & 3;
    const int quad = lane >> 4;
    const int kq   = quad * 8;
    const int nl   = lane & 15;
    const int u    = ut * 16 + nl;
    const int ur   = (u < H) ? u : (H - 1);
    const int b0   = blockIdx.x * BTILE;
    const float blin = b_lin[0];
    const int rowA = (quad & 1) * 4 + (quad >> 1) * 2;   // this quad's 2 batch-rows
    const int arow = quad * 4;             // A-ring row this quad WRITES (relocated)
    const int kc   = lane & 31;            // head: k-phase
    const int bhead= 2 * ut + (lane >> 5); // head: this lane's batch

    // ---- LDS init + input staging ----
    {
        unsigned short* p0 = &sA1h[0][0][0];
        unsigned short* p2 = &sA2h[0][0][0];
        for (int i = tid; i < 2 * 16 * AST; i += NTHR) { p0[i] = 0; p2[i] = 0; }
        float* pf = &sH2f[0][0][0];
        for (int i = tid; i < 2 * 64 * H2ST; i += NTHR) pf[i] = 0.0f;
        if (tid < 16) sXlo[tid >> 3][tid & 7] = 0.0f;
        if (tid < 64) sWlin[tid] = (tid < H) ? W_lin[tid] : 0.0f;
        // stage input tile: 8 rows x 512 f32 = 1024 float4, coalesced
        for (int i = tid; i < BTILE * (TIN / 4); i += NTHR) {
            const int r = i >> 7, c = i & 127;
            *(float4v*)&sIn[r][c * 4] =
                *(const float4v*)&input[(size_t)(b0 + r) * TIN + c * 4];
        }
    }
    __syncthreads();
    if (tid < 8) {   // x(0) -> slot 0: bf16 hi in A col 51 (relocated row), residual
        unsigned short hh; float lo;
        bf16split(sIn[tid][0], hh, lo);
        sA1h[0][(tid & 2) ? tid + 6 : tid][51] = hh;
        sXlo[0][tid] = lo;
    }
    __syncthreads();

    if (wv < 4) {
        // ================= LAYER-1 WAVES =================
        short8 B1h[4][2];
        float zb1[4], wxf[4];
        #pragma unroll
        for (int g = 0; g < 4; ++g) {
            #pragma unroll
            for (int kt = 0; kt < 2; ++kt)
                #pragma unroll
                for (int j = 0; j < 8; ++j)
                    B1h[g][kt][j] = (short)bf16rnd(b1val(kt * 32 + kq + j, u, g, W_hh1, W_ih1));
            const int r = g * H + ur;
            zb1[g] = b_ih1[r] + b_hh1[r];
            wxf[g] = W_ih1[r];             // f32 x-weight for residual fix
        }
        float c1[2] = {0, 0};

        auto l1work = [&](int rs, int ws) __attribute__((always_inline)) {
            short8 a0h = *(const short8*)&sA1h[rs][nl][kq];
            short8 a1h = *(const short8*)&sA1h[rs][nl][32 + kq];
            float2 xl = *(const float2*)&sXlo[rs][rowA];   // residuals for my 2 rows
            float4v C[4];
            #pragma unroll
            for (int g = 0; g < 4; ++g) {
                float4v c = {zb1[g], zb1[g], zb1[g], zb1[g]};
                c = MFMA(a0h, B1h[g][0], c, 0, 0, 0);
                c = MFMA(a1h, B1h[g][1], c, 0, 0, 0);
                C[g] = c;
            }
            float h1v[2];
            #pragma unroll
            for (int j = 0; j < 2; ++j) {
                const float xr = j ? xl.y : xl.x;
                float I = sigf  (C[0][j] + wxf[0] * xr);
                float F = sigf  (C[1][j] + wxf[1] * xr);
                float G = tanhf_(C[2][j] + wxf[2] * xr);
                float O = sigf  (C[3][j] + wxf[3] * xr);
                c1[j] = F * c1[j] + I * G;
                h1v[j] = O * tanhf_(c1[j]);
            }
            if (u < H) {
                const unsigned int pk = bf16pk(h1v[0], h1v[1]);
                sA1h[ws][arow][u]     = (unsigned short)pk;
                sA1h[ws][arow + 1][u] = (unsigned short)(pk >> 16);
            }
        };

        // ---- pipelined teacher-forced phase (static rs/ws) ----
        for (int s = 0; s < TIN; ++s) {
            if ((s & 1) == 0) l1work(0, 1);
            else              l1work(1, 0);
            __syncthreads();
        }
        // ---- serial autoregressive tail ----
        for (int s = TIN; s <= TTOT; ++s) {
            const int rs = s & 1, ws = rs ^ 1;
            __syncthreads();               // B1: L2 finished h2(s-1) -> sH2f[rs]
            __syncthreads();               // B2: aux wrote x(s)
            if (s < TTOT) l1work(rs, ws);
            __syncthreads();               // B3: h1(s) visible
        }
    } else if (wv < 8) {
        // ================= LAYER-2 WAVES =================
        short8 B2h[4][4];
        float zb2[4];
        #pragma unroll
        for (int g = 0; g < 4; ++g) {
            #pragma unroll
            for (int kt = 0; kt < 4; ++kt)
                #pragma unroll
                for (int j = 0; j < 8; ++j)
                    B2h[g][kt][j] = (short)bf16rnd(b2val(kt * 32 + kq + j, u, g, W_ih2, W_hh2));
            const int r = g * H + ur;
            zb2[g] = b_ih2[r] + b_hh2[r];
        }
        float c2[2] = {0, 0};

        auto l2work = [&](int rs, int ws) __attribute__((always_inline)) {
            short8 f0h = *(const short8*)&sA1h[rs][nl][kq];
            short8 f1h = *(const short8*)&sA1h[rs][nl][32 + kq];
            short8 f2h = *(const short8*)&sA2h[rs][nl][kq];
            short8 f3h = *(const short8*)&sA2h[rs][nl][32 + kq];
            float4v C[4];
            #pragma unroll
            for (int g = 0; g < 4; ++g) {
                float4v c = {zb2[g], zb2[g], zb2[g], zb2[g]};
                c = MFMA(f0h, B2h[g][0], c, 0, 0, 0);
                c = MFMA(f1h, B2h[g][1], c, 0, 0, 0);
                c = MFMA(f2h, B2h[g][2], c, 0, 0, 0);
                c = MFMA(f3h, B2h[g][3], c, 0, 0, 0);
                C[g] = c;
            }
            float h2v[2];
            #pragma unroll
            for (int j = 0; j < 2; ++j) {
                float I = sigf  (C[0][j]);
                float F = sigf  (C[1][j]);
                float G = tanhf_(C[2][j]);
                float O = sigf  (C[3][j]);
                c2[j] = F * c2[j] + I * G;
                h2v[j] = O * tanhf_(c2[j]);
            }
            if (u < H) {
                const unsigned int pk = bf16pk(h2v[0], h2v[1]);
                sA2h[ws][arow][u]     = (unsigned short)pk;
                sA2h[ws][arow + 1][u] = (unsigned short)(pk >> 16);
                sH2f[rs][u][rowA]     = h2v[0];
                sH2f[rs][u][rowA + 1] = h2v[1];
            }
        };

        // ---- pipelined teacher-forced phase ----
        for (int s = 0; s < TIN; ++s) {
            if ((s & 1) == 0) { if (s) l2work(0, 1); }
            else              l2work(1, 0);
            __syncthreads();
        }
        // ---- serial tail ----
        for (int s = TIN; s <= TTOT; ++s) {
            const int rs = s & 1, ws = rs ^ 1;
            l2work(rs, ws);
            __syncthreads();               // B1
            __syncthreads();               // B2
            __syncthreads();               // B3
        }
    } else {
        // ================= AUX WAVES: head + x staging + feedback =================
        auto headw = [&](int slot, int outt) __attribute__((always_inline)) -> float {
            float p = sWlin[kc]      * sH2f[slot][kc][bhead]
                    + sWlin[kc + 32] * sH2f[slot][kc + 32][bhead];
            p += __shfl_xor(p, 1);  p += __shfl_xor(p, 2);  p += __shfl_xor(p, 4);
            p += __shfl_xor(p, 8);  p += __shfl_xor(p, 16);
            float val = p + blin;
            if (kc == 0) sOut[bhead][outt] = val;
            return val;
        };

        // ---- teacher phase: head(s-2) + stage x(s+1) ----
        for (int s = 0; s < TIN; ++s) {
            const int ws = (s & 1) ? 0 : 1;
            if (s >= 2) headw(ws, s - 2);      // sH2f[ws] written last interval
            if ((wv == 8) && (lane < 8) && (s + 1 < TIN)) {
                unsigned short hh; float lo; bf16split(sIn[lane][s + 1], hh, lo);
                sA1h[ws][(lane & 2) ? lane + 6 : lane][51] = hh;
                sXlo[ws][lane] = lo;
            }
            __syncthreads();
        }
        // ---- serial tail: head(s-1) + feedback x(s) ----
        for (int s = TIN; s <= TTOT; ++s) {
            const int rs = s & 1, ws = rs ^ 1;
            __syncthreads();               // B1: h2(s-1) -> sH2f[rs] visible
            {
                float val = headw(rs, s - 1);
                if (kc == 0 && s < TTOT) { // feedback x(s) = out(s-1)
                    unsigned short hh; float lo; bf16split(val, hh, lo);
                    sA1h[rs][(bhead & 2) ? bhead + 6 : bhead][51] = hh;
                    sXlo[rs][bhead] = lo;
                }
                if (s == TIN) headw(ws, s - 2);   // gap: out(TIN-2)
            }
            __syncthreads();               // B2: x(s) visible
            __syncthreads();               // B3
        }
    }

    // ---- write buffered outputs back: 8 rows x 544 f32, float4 coalesced ----
    __syncthreads();
    for (int i = tid; i < BTILE * (TTOT / 4); i += NTHR) {
        const int r = i / (TTOT / 4);
        const int c = i - r * (TTOT / 4);
        *(float4v*)&out[(size_t)(b0 + r) * TTOT + c * 4] =
            *(const float4v*)&sOut[r][c * 4];
    }
}

extern "C" void kernel_launch(void* const* d_in, const int* in_sizes, int n_in,
                              void* d_out, int out_size, void* d_ws, size_t ws_size,
                              hipStream_t stream) {
    const float* input = (const float*)d_in[0];
    const float* W_ih1 = (const float*)d_in[1];
    const float* W_hh1 = (const float*)d_in[2];
    const float* b_ih1 = (const float*)d_in[3];
    const float* b_hh1 = (const float*)d_in[4];
    const float* W_ih2 = (const float*)d_in[5];
    const float* W_hh2 = (const float*)d_in[6];
    const float* b_ih2 = (const float*)d_in[7];
    const float* b_hh2 = (const float*)d_in[8];
    const float* W_lin = (const float*)d_in[9];
    const float* b_lin = (const float*)d_in[10];
    // d_in[11] = future (=32), compiled in.
    float* out = (float*)d_out;

    lstm_seq<<<dim3(256), dim3(NTHR), 0, stream>>>(input, W_ih1, W_hh1, b_ih1, b_hh1,
                                                   W_ih2, W_hh2, b_ih2, b_hh2,
                                                   W_lin, b_lin, out);
}